// Round 7
// baseline (663.458 us; speedup 1.0000x reference)
//
#include <hip/hip_runtime.h>
#include <stdint.h>

#define N_NODES 100000
#define N_EDGES 3200000
#define DIM 128
#define NPAD 100032   // 1563 * 64
#define DEGN 100352   // 98 * 1024, padded degree/rowptr array length
#define EPB 4096      // edges per count/scatter block (16/thread)
#define PASSU32 3200000   // u32 per pass table: 100000 nodes * 32 u32 (64 dims)
#define WSTR 140      // LDS row stride in shorts (280 B) -> ~2-way banks, free

typedef short short8 __attribute__((ext_vector_type(8)));
typedef float f32x4 __attribute__((ext_vector_type(4)));
typedef float f32x2 __attribute__((ext_vector_type(2)));

__device__ __forceinline__ short f2bf(float x) {
    uint32_t u = __builtin_bit_cast(uint32_t, x);
    u += 0x7fffu + ((u >> 16) & 1u);   // round-to-nearest-even
    return (short)(u >> 16);
}
__device__ __forceinline__ float bflo(uint32_t p) {
    return __builtin_bit_cast(float, p << 16);
}
__device__ __forceinline__ float bfhi(uint32_t p) {
    return __builtin_bit_cast(float, p & 0xffff0000u);
}
__device__ __forceinline__ uint32_t pack2(float x, float y) {
    return (uint32_t)(uint16_t)f2bf(x) | ((uint32_t)(uint16_t)f2bf(y) << 16);
}
__device__ __forceinline__ f32x2 up2(uint32_t p) {
    return (f32x2){ bflo(p), bfhi(p) };
}

// ---- K1: fused prep: feat->bf16 cast (PASS-MAJOR), W transpose, zero ----
// featp layout: featp[p][node][32 u32]  (p-th 64-dim half, 128 B per row)
__global__ __launch_bounds__(256) void prep_kernel(const float* __restrict__ feat,
                                                   uint32_t* __restrict__ featp,
                                                   const float* __restrict__ w1,
                                                   const float* __restrict__ w2,
                                                   short* __restrict__ w1t,
                                                   short* __restrict__ w2t,
                                                   int* __restrict__ deg) {
    int b = blockIdx.x, t = threadIdx.x;
    if (b < 12500) {                       // cast: 3.2M float4s
        int i = b * 256 + t;
        float4 f = ((const float4*)feat)[i];
        int node = i >> 5;                 // 32 float4s per 128-dim row
        int qi = i & 31;                   // which float4 in row
        int p = qi >> 4;                   // dim half
        int ld = qi & 15;                  // float4 within half (16 per half)
        uint32_t* o = &featp[p * PASSU32 + node * 32 + ld * 2];
        o[0] = pack2(f.x, f.y);
        o[1] = pack2(f.z, f.w);
    } else if (b < 12564) {                // weight transpose: 16384 elems
        int i = (b - 12500) * 256 + t;
        int k = i >> 7, n = i & 127;
        w1t[n * DIM + k] = f2bf(w1[i]);
        w2t[n * DIM + k] = f2bf(w2[i]);
    } else {                               // zero deg (100352 ints, 392 blocks)
        int i = (b - 12564) * 256 + t;
        deg[i] = 0;
    }
}

// ---- K2: degree count: fire-and-forget atomics, 32-deep chains ----------
__global__ __launch_bounds__(256) void count_kernel(const int* __restrict__ dst,
                                                    int* __restrict__ deg) {
    int e0 = blockIdx.x * EPB + threadIdx.x;
#pragma unroll
    for (int i = 0; i < 16; i++) {
        int e = e0 + i * 256;
        if (e < N_EDGES) atomicAdd(&deg[dst[e]], 1);
    }
}

// ---- K3a: per-1024-chunk sums ------------------------------------------
__global__ __launch_bounds__(1024) void scan1_kernel(const int* __restrict__ deg,
                                                     int* __restrict__ bsum) {
    __shared__ int s[1024];
    int t = threadIdx.x;
    s[t] = deg[blockIdx.x * 1024 + t];
    __syncthreads();
    for (int d = 512; d > 0; d >>= 1) {
        if (t < d) s[t] += s[t + d];
        __syncthreads();
    }
    if (t == 0) bsum[blockIdx.x] = s[0];
}

// ---- K3b: scan the 98 chunk sums ---------------------------------------
__global__ __launch_bounds__(128) void scan2_kernel(const int* __restrict__ bsum,
                                                    int* __restrict__ boff) {
    __shared__ int s[128];
    int t = threadIdx.x;
    int v = (t < 98) ? bsum[t] : 0;
    s[t] = v;
    __syncthreads();
    for (int d = 1; d < 128; d <<= 1) {
        int x = (t >= d) ? s[t - d] : 0;
        __syncthreads();
        s[t] += x;
        __syncthreads();
    }
    if (t < 98) boff[t] = s[t] - v;     // exclusive
}

// ---- K3c: per-chunk exclusive scan -> rowptr + rowcur ------------------
__global__ __launch_bounds__(1024) void scan3_kernel(const int* __restrict__ deg,
                                                     const int* __restrict__ boff,
                                                     int* __restrict__ rowptr,
                                                     int* __restrict__ rowcur) {
    __shared__ int s[1024];
    int b = blockIdx.x, t = threadIdx.x;
    int i = b * 1024 + t;
    int v = deg[i];
    s[t] = v;
    __syncthreads();
    for (int d = 1; d < 1024; d <<= 1) {
        int x = (t >= d) ? s[t - d] : 0;
        __syncthreads();
        s[t] += x;
        __syncthreads();
    }
    int excl = s[t] - v + boff[b];
    rowptr[i] = excl;
    rowcur[i] = excl;
}

// ---- K3d: scatter edges into CSR slots ---------------------------------
__global__ __launch_bounds__(256) void scatter_kernel(const int* __restrict__ src,
                                                      const int* __restrict__ dst,
                                                      int* __restrict__ rowcur,
                                                      int* __restrict__ csr) {
    int e0 = blockIdx.x * EPB + threadIdx.x;
#pragma unroll
    for (int i = 0; i < 16; i++) {
        int e = e0 + i * 256;
        if (e < N_EDGES) {
            int dv = dst[e];
            int sv = src[e];
            int pos = atomicAdd(&rowcur[dv], 1);
            csr[pos] = sv;
        }
    }
}

// load helper: broadcast row index from lane `sl`, load 16B of 128B row
#define LDQ(qv, sl) do { int _i = __shfl(u, (sl)); \
    qv = *(const uint4*)&featp[_i * 32 + col8 * 4]; } while (0)

#define ACC8(q) do { \
    A01 += up2((q).x); A23 += up2((q).y); A45 += up2((q).z); A67 += up2((q).w); } while (0)

// ---- K4: dim-split 2-pass gather; 8 rows per dwordx4 instruction --------
// pass p reads featp table p (12.8 MB working set) and writes hbf half-row
__global__ __launch_bounds__(256) void gather_kernel(const uint32_t* __restrict__ featp,
                                                     const int* __restrict__ rowptr,
                                                     const int* __restrict__ csr,
                                                     const float* __restrict__ eps,
                                                     uint32_t* __restrict__ hbf,
                                                     int poff) {   // p*32 (u32 offset in hbf row)
    int wid = blockIdx.x * 4 + (threadIdx.x >> 6);
    int lane = threadIdx.x & 63;
    int eighth = lane >> 3;     // which of 8 rows in a load instruction
    int col8 = lane & 7;        // uint4 column: 8 lanes x 16B = 128B row
    if (wid >= N_NODES) {       // padding rows for the MLP tile
        if (wid < NPAD && lane < 32) hbf[wid * 64 + poff + lane] = 0;
        return;
    }
    float e1 = 1.0f + eps[0];
    uint4 sf = *(const uint4*)&featp[wid * 32 + col8 * 4];  // self half-row
    f32x2 A01 = (f32x2){0.f, 0.f}, A23 = (f32x2){0.f, 0.f};
    f32x2 A45 = (f32x2){0.f, 0.f}, A67 = (f32x2){0.f, 0.f};
    int start = rowptr[wid], end = rowptr[wid + 1];
    for (int base = start; base < end; base += 64) {
        int m = min(64, end - base);
        int u = (lane < m) ? csr[base + lane] : 0;
        int j = 0;
        for (; j + 32 <= m; j += 32) {   // full 32-edge chunk: 4 instrs, 4 KB
            uint4 q0, q1, q2, q3;
            LDQ(q0, j + eighth);
            LDQ(q1, j + 8 + eighth);
            LDQ(q2, j + 16 + eighth);
            LDQ(q3, j + 24 + eighth);
            ACC8(q0); ACC8(q1); ACC8(q2); ACC8(q3);
        }
        int r = m - j;
        if (r > 0) {                      // graded tail: 4/3/2/1 instructions
            int mm = m - 1;
            if (r > 24) {
                uint4 q0, q1, q2, q3;
                int p3 = j + 24 + eighth;
                LDQ(q0, j + eighth); LDQ(q1, j + 8 + eighth);
                LDQ(q2, j + 16 + eighth); LDQ(q3, min(p3, mm));
                ACC8(q0); ACC8(q1); ACC8(q2);
                if (p3 < m) ACC8(q3);
            } else if (r > 16) {
                uint4 q0, q1, q2;
                int p2 = j + 16 + eighth;
                LDQ(q0, j + eighth); LDQ(q1, j + 8 + eighth);
                LDQ(q2, min(p2, mm));
                ACC8(q0); ACC8(q1);
                if (p2 < m) ACC8(q2);
            } else if (r > 8) {
                uint4 q0, q1;
                int p1 = j + 8 + eighth;
                LDQ(q0, j + eighth); LDQ(q1, min(p1, mm));
                ACC8(q0);
                if (p1 < m) ACC8(q1);
            } else {
                uint4 q0;
                int p0 = j + eighth;
                LDQ(q0, min(p0, mm));
                if (p0 < m) ACC8(q0);
            }
        }
    }
    // reduce across the 8 row-groups (xor 8, 16, 32)
    float a0 = A01.x, a1 = A01.y, a2 = A23.x, a3 = A23.y;
    float a4 = A45.x, a5 = A45.y, a6 = A67.x, a7 = A67.y;
    a0 += __shfl_xor(a0, 8);  a1 += __shfl_xor(a1, 8);
    a2 += __shfl_xor(a2, 8);  a3 += __shfl_xor(a3, 8);
    a4 += __shfl_xor(a4, 8);  a5 += __shfl_xor(a5, 8);
    a6 += __shfl_xor(a6, 8);  a7 += __shfl_xor(a7, 8);
    a0 += __shfl_xor(a0, 16); a1 += __shfl_xor(a1, 16);
    a2 += __shfl_xor(a2, 16); a3 += __shfl_xor(a3, 16);
    a4 += __shfl_xor(a4, 16); a5 += __shfl_xor(a5, 16);
    a6 += __shfl_xor(a6, 16); a7 += __shfl_xor(a7, 16);
    a0 += __shfl_xor(a0, 32); a1 += __shfl_xor(a1, 32);
    a2 += __shfl_xor(a2, 32); a3 += __shfl_xor(a3, 32);
    a4 += __shfl_xor(a4, 32); a5 += __shfl_xor(a5, 32);
    a6 += __shfl_xor(a6, 32); a7 += __shfl_xor(a7, 32);
    if (eighth == 0) {         // lanes 0-7 store the 128B half-row
        a0 += e1 * bflo(sf.x); a1 += e1 * bfhi(sf.x);
        a2 += e1 * bflo(sf.y); a3 += e1 * bfhi(sf.y);
        a4 += e1 * bflo(sf.z); a5 += e1 * bfhi(sf.z);
        a6 += e1 * bflo(sf.w); a7 += e1 * bfhi(sf.w);
        uint4 w;
        w.x = pack2(a0, a1); w.y = pack2(a2, a3);
        w.z = pack2(a4, a5); w.w = pack2(a6, a7);
        *(uint4*)&hbf[wid * 64 + poff + col8 * 4] = w;
    }
}

// ---- K5: fused 2-layer MLP; weights staged ONCE in LDS, 8 indep waves ---
// 256 blocks x 512 thr, 1 block/CU. LDS: 2x35840 (weights) + 8x4480 (h1)
__global__ __launch_bounds__(512) void mlp_kernel(const short* __restrict__ hbf,
                                                  const short* __restrict__ w1t,
                                                  const short* __restrict__ w2t,
                                                  const float* __restrict__ b1,
                                                  const float* __restrict__ b2,
                                                  float* __restrict__ out) {
    __shared__ __align__(16) short w1s[128 * WSTR];
    __shared__ __align__(16) short w2s[128 * WSTR];
    __shared__ __align__(16) short h1s[8][16 * WSTR];
    const int t = threadIdx.x;
    // stage both weight tables into LDS (once per block)
    for (int c = t; c < 2048; c += 512) {          // 2048 short8 chunks/table
        int row = c >> 4, cp = c & 15;
        *(short8*)&w1s[row * WSTR + cp * 8] = *(const short8*)&w1t[row * DIM + cp * 8];
        *(short8*)&w2s[row * WSTR + cp * 8] = *(const short8*)&w2t[row * DIM + cp * 8];
    }
    const int wave = t >> 6;
    const int lane = t & 63;
    const int l15 = lane & 15;
    const int quad = lane >> 4;
    short* h1w = &h1s[wave][0];

    float b1v[8], b2v[8];
#pragma unroll
    for (int n = 0; n < 8; n++) {
        b1v[n] = b1[n * 16 + l15];
        b2v[n] = b2[n * 16 + l15];
    }
    __syncthreads();   // weights staged; waves independent from here on

    const int ngroups = NPAD / 16;                 // 6252 16-row groups
    for (int g = blockIdx.x * 8 + wave; g < ngroups; g += gridDim.x * 8) {
        int row0 = g * 16;
        f32x4 acc[8];
#pragma unroll
        for (int n = 0; n < 8; n++) acc[n] = (f32x4){0.f, 0.f, 0.f, 0.f};
#pragma unroll
        for (int kb = 0; kb < DIM; kb += 32) {
            short8 a = *(const short8*)&hbf[(row0 + l15) * DIM + kb + quad * 8];
#pragma unroll
            for (int n = 0; n < 8; n++) {
                short8 b = *(const short8*)&w1s[(n * 16 + l15) * WSTR + kb + quad * 8];
                acc[n] = __builtin_amdgcn_mfma_f32_16x16x32_bf16(a, b, acc[n], 0, 0, 0);
            }
        }
#pragma unroll
        for (int n = 0; n < 8; n++) {
#pragma unroll
            for (int r = 0; r < 4; r++) {
                float v = acc[n][r] + b1v[n];
                v = v > 0.f ? v : 0.f;
                h1w[(quad * 4 + r) * WSTR + n * 16 + l15] = f2bf(v);
            }
        }
        // same-wave LDS RAW: compiler inserts lgkmcnt wait (no barrier needed)
        f32x4 acc2[8];
#pragma unroll
        for (int n = 0; n < 8; n++) acc2[n] = (f32x4){0.f, 0.f, 0.f, 0.f};
#pragma unroll
        for (int kb = 0; kb < DIM; kb += 32) {
            short8 a2 = *(const short8*)&h1w[l15 * WSTR + kb + quad * 8];
#pragma unroll
            for (int n = 0; n < 8; n++) {
                short8 b = *(const short8*)&w2s[(n * 16 + l15) * WSTR + kb + quad * 8];
                acc2[n] = __builtin_amdgcn_mfma_f32_16x16x32_bf16(a2, b, acc2[n], 0, 0, 0);
            }
        }
#pragma unroll
        for (int n = 0; n < 8; n++) {
#pragma unroll
            for (int r = 0; r < 4; r++) {
                int row = row0 + quad * 4 + r;
                if (row < N_NODES)
                    out[row * DIM + n * 16 + l15] = acc2[n][r] + b2v[n];
            }
        }
    }
}

extern "C" void kernel_launch(void* const* d_in, const int* in_sizes, int n_in,
                              void* d_out, int out_size, void* d_ws, size_t ws_size,
                              hipStream_t stream) {
    const float* feat = (const float*)d_in[0];
    const int* src    = (const int*)d_in[1];
    const int* dst    = (const int*)d_in[2];
    const float* eps  = (const float*)d_in[3];
    const float* W1   = (const float*)d_in[4];
    const float* b1   = (const float*)d_in[5];
    const float* W2   = (const float*)d_in[6];
    const float* b2   = (const float*)d_in[7];
    float* out = (float*)d_out;

    char* ws = (char*)d_ws;
    int*      deg     = (int*)ws;                          //   401,408 B (100352 ints)
    int*      rowptr  = (int*)(ws + 401408);               //   401,408 B
    int*      rowcur  = (int*)(ws + 802816);               //   401,408 B
    int*      bsum    = (int*)(ws + 1204224);              //       512 B
    int*      boff    = (int*)(ws + 1204736);              //       512 B
    int*      csr     = (int*)(ws + 1205248);              // 12,800,000 B
    uint32_t* featp   = (uint32_t*)(ws + 14005248);        // 25,600,000 B (2 pass tables)
    uint32_t* hbf     = (uint32_t*)(ws + 39605248);        // 25,608,192 B
    short*    w1t     = (short*)(ws + 65213440);           //     32,768 B
    short*    w2t     = (short*)(ws + 65246208);           // ends 65,278,976 B

    prep_kernel<<<12956, 256, 0, stream>>>(feat, featp, W1, W2, w1t, w2t, deg);
    count_kernel<<<(N_EDGES + EPB - 1) / EPB, 256, 0, stream>>>(dst, deg);
    scan1_kernel<<<DEGN / 1024, 1024, 0, stream>>>(deg, bsum);
    scan2_kernel<<<1, 128, 0, stream>>>(bsum, boff);
    scan3_kernel<<<DEGN / 1024, 1024, 0, stream>>>(deg, boff, rowptr, rowcur);
    scatter_kernel<<<(N_EDGES + EPB - 1) / EPB, 256, 0, stream>>>(src, dst, rowcur, csr);
    gather_kernel<<<NPAD / 4, 256, 0, stream>>>(featp, rowptr, csr, eps, hbf, 0);
    gather_kernel<<<NPAD / 4, 256, 0, stream>>>(featp + PASSU32, rowptr, csr, eps, hbf, 32);
    mlp_kernel<<<256, 512, 0, stream>>>((const short*)hbf, w1t, w2t, b1, b2, out);
}

// Round 9
// 305.171 us; speedup vs baseline: 2.1741x; 2.1741x over previous
//
#include <hip/hip_runtime.h>
#include <stdint.h>

#define N_NODES 100000
#define N_EDGES 3200000
#define DIM 128
#define NPAD 100032   // 1563 * 64
#define NBINS 391     // ceil(100000 / 256) -- 256 nodes per bin
#define NBLK 782      // edge blocks: ceil(3.2M / 4096)
#define BCAP 10176    // bin capacity; mean 8184, +22 sigma
#define EPB 4096      // edges per bin/hist block (16/thread)
#define PASSU32 3200000   // u32 per pass table: 100000 nodes * 32 u32 (64 dims)
#define WSTR 140      // LDS row stride in shorts (280 B) -> ~2-way banks, free

typedef short short8 __attribute__((ext_vector_type(8)));
typedef float f32x4 __attribute__((ext_vector_type(4)));
typedef float f32x2 __attribute__((ext_vector_type(2)));

__device__ __forceinline__ short f2bf(float x) {
    uint32_t u = __builtin_bit_cast(uint32_t, x);
    u += 0x7fffu + ((u >> 16) & 1u);   // round-to-nearest-even
    return (short)(u >> 16);
}
__device__ __forceinline__ float bflo(uint32_t p) {
    return __builtin_bit_cast(float, p << 16);
}
__device__ __forceinline__ float bfhi(uint32_t p) {
    return __builtin_bit_cast(float, p & 0xffff0000u);
}
__device__ __forceinline__ uint32_t pack2(float x, float y) {
    return (uint32_t)(uint16_t)f2bf(x) | ((uint32_t)(uint16_t)f2bf(y) << 16);
}
__device__ __forceinline__ f32x2 up2(uint32_t p) {
    return (f32x2){ bflo(p), bfhi(p) };
}

// ---- K1: fused prep: feat->bf16 cast (PASS-MAJOR), W transpose ----------
// featp layout: featp[p][node][32 u32]  (p-th 64-dim half, 128 B per row)
__global__ __launch_bounds__(256) void prep_kernel(const float* __restrict__ feat,
                                                   uint32_t* __restrict__ featp,
                                                   const float* __restrict__ w1,
                                                   const float* __restrict__ w2,
                                                   short* __restrict__ w1t,
                                                   short* __restrict__ w2t) {
    int b = blockIdx.x, t = threadIdx.x;
    if (b < 12500) {                       // cast: 3.2M float4s
        int i = b * 256 + t;
        float4 f = ((const float4*)feat)[i];
        int node = i >> 5;                 // 32 float4s per 128-dim row
        int qi = i & 31;                   // which float4 in row
        int p = qi >> 4;                   // dim half
        int ld = qi & 15;                  // float4 within half (16 per half)
        uint32_t* o = &featp[p * PASSU32 + node * 32 + ld * 2];
        o[0] = pack2(f.x, f.y);
        o[1] = pack2(f.z, f.w);
    } else {                               // weight transpose: 16384 elems
        int i = (b - 12500) * 256 + t;
        int k = i >> 7, n = i & 127;
        w1t[n * DIM + k] = f2bf(w1[i]);
        w2t[n * DIM + k] = f2bf(w2[i]);
    }
}

// ---- K2a: per-block bin histogram (no device atomics) -------------------
__global__ __launch_bounds__(256) void hist_kernel(const int* __restrict__ dst,
                                                   int* __restrict__ ghist) {
    __shared__ int hist[NBINS];
    int t = threadIdx.x;
    for (int i = t; i < NBINS; i += 256) hist[i] = 0;
    __syncthreads();
    int e0 = blockIdx.x * EPB;
    int nn = min(EPB, N_EDGES - e0);
    for (int i = t; i < nn; i += 256) atomicAdd(&hist[dst[e0 + i] >> 8], 1);
    __syncthreads();
    for (int b = t; b < NBINS; b += 256)
        ghist[b * NBLK + blockIdx.x] = hist[b];
}

// ---- K2b: per-bin scan over blocks -> deterministic offsets -------------
__global__ __launch_bounds__(1024) void offset_kernel(const int* __restrict__ ghist,
                                                      int* __restrict__ goff,
                                                      int* __restrict__ bincnt) {
    __shared__ int s[1024];
    int b = blockIdx.x, t = threadIdx.x;
    int v = (t < NBLK) ? ghist[b * NBLK + t] : 0;
    s[t] = v;
    __syncthreads();
    for (int d = 1; d < 1024; d <<= 1) {
        int x = (t >= d) ? s[t - d] : 0;
        __syncthreads();
        s[t] += x;
        __syncthreads();
    }
    if (t < NBLK) goff[b * NBLK + t] = s[t] - v;   // exclusive over blocks
    if (t == NBLK - 1) bincnt[b] = s[t];           // bin total
}

// ---- K2c: bin edges by dst>>8, LDS counting-sort, coalesced write-out ---
// identical to the proven LDS-sort kernel, but gbase is a plain LOAD
__global__ __launch_bounds__(256) void bin_kernel(const int* __restrict__ src,
                                                  const int* __restrict__ dst,
                                                  const int* __restrict__ goff,
                                                  uint32_t* __restrict__ binpair) {
    __shared__ int hist[512];
    __shared__ int scanv[512];
    __shared__ int scan256[256];
    __shared__ int gbase[NBINS];
    __shared__ int cursor[NBINS];
    __shared__ uint32_t sorted[EPB];
    __shared__ int saddr[EPB];
    int t = threadIdx.x;
    for (int i = t; i < 512; i += 256) hist[i] = 0;
    __syncthreads();
    int e0 = blockIdx.x * EPB;
    int nn = min(EPB, N_EDGES - e0);
    int d[16];
#pragma unroll
    for (int i = 0; i < 16; i++) {
        int idx = i * 256 + t;
        d[i] = (idx < nn) ? dst[e0 + idx] : -1;
        if (d[i] >= 0) atomicAdd(&hist[d[i] >> 8], 1);
    }
    __syncthreads();
    int h0 = hist[2 * t], h1 = hist[2 * t + 1];
    scan256[t] = h0 + h1;
    __syncthreads();
    for (int dd = 1; dd < 256; dd <<= 1) {
        int v = (t >= dd) ? scan256[t - dd] : 0;
        __syncthreads();
        scan256[t] += v;
        __syncthreads();
    }
    int pairExcl = scan256[t] - (h0 + h1);
    scanv[2 * t] = pairExcl;
    scanv[2 * t + 1] = pairExcl + h0;
    for (int b = t; b < NBINS; b += 256) {
        gbase[b] = goff[b * NBLK + blockIdx.x];    // deterministic, no atomic
        cursor[b] = 0;
    }
    __syncthreads();
#pragma unroll
    for (int i = 0; i < 16; i++) {
        if (d[i] >= 0) {
            int b = d[i] >> 8;
            int slot = atomicAdd(&cursor[b], 1);
            int p = scanv[b] + slot;
            int g = gbase[b] + slot;
            int e = e0 + i * 256 + t;
            sorted[p] = (uint32_t)src[e] | ((uint32_t)(d[i] & 255) << 24);
            saddr[p] = (g < BCAP) ? (b * BCAP + g) : -1;
        }
    }
    __syncthreads();
    for (int i = t; i < nn; i += 256) {
        int a = saddr[i];
        if (a >= 0) binpair[a] = sorted[i];
    }
}

// ---- K3: per-bin counting sort -> CSR (1024 thr, LDS-staged coalesced) --
__global__ __launch_bounds__(1024) void csr_kernel(const int* __restrict__ bincnt,
                                                   const uint32_t* __restrict__ binpair,
                                                   int* __restrict__ rowptr,
                                                   int* __restrict__ csr) {
    __shared__ int hist[256];
    __shared__ int cursor[256];
    __shared__ int sc[256];
    __shared__ int red[256];
    __shared__ int binbase_s;
    __shared__ int sorted_s[BCAP];
    int b = blockIdx.x;
    int t = threadIdx.x;
    if (t < 256) {
        int partial = 0;
        for (int j = t; j < b; j += 256) partial += min(bincnt[j], BCAP);
        red[t] = partial;
        hist[t] = 0;
    }
    __syncthreads();
    for (int dd = 128; dd > 0; dd >>= 1) {
        if (t < dd) red[t] += red[t + dd];
        __syncthreads();
    }
    if (t == 0) binbase_s = red[0];
    __syncthreads();
    int binbase = binbase_s;
    int cntb = min(bincnt[b], BCAP);
    const uint32_t* pairs = binpair + (size_t)b * BCAP;
    for (int i = t; i < cntb; i += 1024)
        atomicAdd(&hist[pairs[i] >> 24], 1);
    __syncthreads();
    int val = 0;
    if (t < 256) { val = hist[t]; sc[t] = val; }
    __syncthreads();
    for (int dd = 1; dd < 256; dd <<= 1) {
        int addv = (t < 256 && t >= dd) ? sc[t - dd] : 0;
        __syncthreads();
        if (t < 256) sc[t] += addv;
        __syncthreads();
    }
    if (t < 256) {
        int excl = sc[t] - val;
        rowptr[(b << 8) + t] = binbase + excl;
        cursor[t] = excl;
    }
    __syncthreads();
    for (int i = t; i < cntb; i += 1024) {
        uint32_t p = pairs[i];
        int s2 = atomicAdd(&cursor[p >> 24], 1);
        sorted_s[s2] = (int)(p & 0x00FFFFFFu);
    }
    __syncthreads();
    for (int i = t; i < cntb; i += 1024)
        csr[binbase + i] = sorted_s[i];
}

// load helper: broadcast row index from lane `sl`, load 16B of 128B row
#define LDQ(qv, sl) do { int _i = __shfl(u, (sl)); \
    qv = *(const uint4*)&featp[_i * 32 + col8 * 4]; } while (0)

#define ACC8(q) do { \
    A01 += up2((q).x); A23 += up2((q).y); A45 += up2((q).z); A67 += up2((q).w); } while (0)

// ---- K4: dim-split 2-pass gather; 8 rows per dwordx4 instruction --------
// pass p reads featp table p (12.8 MB working set) and writes hbf half-row
__global__ __launch_bounds__(256) void gather_kernel(const uint32_t* __restrict__ featp,
                                                     const int* __restrict__ rowptr,
                                                     const int* __restrict__ csr,
                                                     const float* __restrict__ eps,
                                                     uint32_t* __restrict__ hbf,
                                                     int poff) {   // p*32 (u32 offset in hbf row)
    int wid = blockIdx.x * 4 + (threadIdx.x >> 6);
    int lane = threadIdx.x & 63;
    int eighth = lane >> 3;     // which of 8 rows in a load instruction
    int col8 = lane & 7;        // uint4 column: 8 lanes x 16B = 128B row
    if (wid >= N_NODES) {       // padding rows for the MLP tile
        if (wid < NPAD && lane < 32) hbf[wid * 64 + poff + lane] = 0;
        return;
    }
    float e1 = 1.0f + eps[0];
    uint4 sf = *(const uint4*)&featp[wid * 32 + col8 * 4];  // self half-row
    f32x2 A01 = (f32x2){0.f, 0.f}, A23 = (f32x2){0.f, 0.f};
    f32x2 A45 = (f32x2){0.f, 0.f}, A67 = (f32x2){0.f, 0.f};
    int start = rowptr[wid], end = rowptr[wid + 1];
    for (int base = start; base < end; base += 64) {
        int m = min(64, end - base);
        int u = (lane < m) ? csr[base + lane] : 0;
        int j = 0;
        for (; j + 32 <= m; j += 32) {   // full 32-edge chunk: 4 instrs, 4 KB
            uint4 q0, q1, q2, q3;
            LDQ(q0, j + eighth);
            LDQ(q1, j + 8 + eighth);
            LDQ(q2, j + 16 + eighth);
            LDQ(q3, j + 24 + eighth);
            ACC8(q0); ACC8(q1); ACC8(q2); ACC8(q3);
        }
        int r = m - j;
        if (r > 0) {                      // graded tail: 4/3/2/1 instructions
            int mm = m - 1;
            if (r > 24) {
                uint4 q0, q1, q2, q3;
                int p3 = j + 24 + eighth;
                LDQ(q0, j + eighth); LDQ(q1, j + 8 + eighth);
                LDQ(q2, j + 16 + eighth); LDQ(q3, min(p3, mm));
                ACC8(q0); ACC8(q1); ACC8(q2);
                if (p3 < m) ACC8(q3);
            } else if (r > 16) {
                uint4 q0, q1, q2;
                int p2 = j + 16 + eighth;
                LDQ(q0, j + eighth); LDQ(q1, j + 8 + eighth);
                LDQ(q2, min(p2, mm));
                ACC8(q0); ACC8(q1);
                if (p2 < m) ACC8(q2);
            } else if (r > 8) {
                uint4 q0, q1;
                int p1 = j + 8 + eighth;
                LDQ(q0, j + eighth); LDQ(q1, min(p1, mm));
                ACC8(q0);
                if (p1 < m) ACC8(q1);
            } else {
                uint4 q0;
                int p0 = j + eighth;
                LDQ(q0, min(p0, mm));
                if (p0 < m) ACC8(q0);
            }
        }
    }
    // reduce across the 8 row-groups (xor 8, 16, 32)
    float a0 = A01.x, a1 = A01.y, a2 = A23.x, a3 = A23.y;
    float a4 = A45.x, a5 = A45.y, a6 = A67.x, a7 = A67.y;
    a0 += __shfl_xor(a0, 8);  a1 += __shfl_xor(a1, 8);
    a2 += __shfl_xor(a2, 8);  a3 += __shfl_xor(a3, 8);
    a4 += __shfl_xor(a4, 8);  a5 += __shfl_xor(a5, 8);
    a6 += __shfl_xor(a6, 8);  a7 += __shfl_xor(a7, 8);
    a0 += __shfl_xor(a0, 16); a1 += __shfl_xor(a1, 16);
    a2 += __shfl_xor(a2, 16); a3 += __shfl_xor(a3, 16);
    a4 += __shfl_xor(a4, 16); a5 += __shfl_xor(a5, 16);
    a6 += __shfl_xor(a6, 16); a7 += __shfl_xor(a7, 16);
    a0 += __shfl_xor(a0, 32); a1 += __shfl_xor(a1, 32);
    a2 += __shfl_xor(a2, 32); a3 += __shfl_xor(a3, 32);
    a4 += __shfl_xor(a4, 32); a5 += __shfl_xor(a5, 32);
    a6 += __shfl_xor(a6, 32); a7 += __shfl_xor(a7, 32);
    if (eighth == 0) {         // lanes 0-7 store the 128B half-row
        a0 += e1 * bflo(sf.x); a1 += e1 * bfhi(sf.x);
        a2 += e1 * bflo(sf.y); a3 += e1 * bfhi(sf.y);
        a4 += e1 * bflo(sf.z); a5 += e1 * bfhi(sf.z);
        a6 += e1 * bflo(sf.w); a7 += e1 * bfhi(sf.w);
        uint4 w;
        w.x = pack2(a0, a1); w.y = pack2(a2, a3);
        w.z = pack2(a4, a5); w.w = pack2(a6, a7);
        *(uint4*)&hbf[wid * 64 + poff + col8 * 4] = w;
    }
}

// ---- K5: fused 2-layer MLP; weights staged ONCE in LDS, 8 indep waves ---
// 256 blocks x 512 thr, 1 block/CU. LDS: 2x35840 (weights) + 8x4480 (h1)
__global__ __launch_bounds__(512) void mlp_kernel(const short* __restrict__ hbf,
                                                  const short* __restrict__ w1t,
                                                  const short* __restrict__ w2t,
                                                  const float* __restrict__ b1,
                                                  const float* __restrict__ b2,
                                                  float* __restrict__ out) {
    __shared__ __align__(16) short w1s[128 * WSTR];
    __shared__ __align__(16) short w2s[128 * WSTR];
    __shared__ __align__(16) short h1s[8][16 * WSTR];
    const int t = threadIdx.x;
    // stage both weight tables into LDS (once per block)
    for (int c = t; c < 2048; c += 512) {          // 2048 short8 chunks/table
        int row = c >> 4, cp = c & 15;
        *(short8*)&w1s[row * WSTR + cp * 8] = *(const short8*)&w1t[row * DIM + cp * 8];
        *(short8*)&w2s[row * WSTR + cp * 8] = *(const short8*)&w2t[row * DIM + cp * 8];
    }
    const int wave = t >> 6;
    const int lane = t & 63;
    const int l15 = lane & 15;
    const int quad = lane >> 4;
    short* h1w = &h1s[wave][0];

    float b1v[8], b2v[8];
#pragma unroll
    for (int n = 0; n < 8; n++) {
        b1v[n] = b1[n * 16 + l15];
        b2v[n] = b2[n * 16 + l15];
    }
    __syncthreads();   // weights staged; waves independent from here on

    const int ngroups = NPAD / 16;                 // 6252 16-row groups
    for (int g = blockIdx.x * 8 + wave; g < ngroups; g += gridDim.x * 8) {
        int row0 = g * 16;
        f32x4 acc[8];
#pragma unroll
        for (int n = 0; n < 8; n++) acc[n] = (f32x4){0.f, 0.f, 0.f, 0.f};
#pragma unroll
        for (int kb = 0; kb < DIM; kb += 32) {
            short8 a = *(const short8*)&hbf[(row0 + l15) * DIM + kb + quad * 8];
#pragma unroll
            for (int n = 0; n < 8; n++) {
                short8 b = *(const short8*)&w1s[(n * 16 + l15) * WSTR + kb + quad * 8];
                acc[n] = __builtin_amdgcn_mfma_f32_16x16x32_bf16(a, b, acc[n], 0, 0, 0);
            }
        }
#pragma unroll
        for (int n = 0; n < 8; n++) {
#pragma unroll
            for (int r = 0; r < 4; r++) {
                float v = acc[n][r] + b1v[n];
                v = v > 0.f ? v : 0.f;
                h1w[(quad * 4 + r) * WSTR + n * 16 + l15] = f2bf(v);
            }
        }
        // same-wave LDS RAW: compiler inserts lgkmcnt wait (no barrier needed)
        f32x4 acc2[8];
#pragma unroll
        for (int n = 0; n < 8; n++) acc2[n] = (f32x4){0.f, 0.f, 0.f, 0.f};
#pragma unroll
        for (int kb = 0; kb < DIM; kb += 32) {
            short8 a2 = *(const short8*)&h1w[l15 * WSTR + kb + quad * 8];
#pragma unroll
            for (int n = 0; n < 8; n++) {
                short8 b = *(const short8*)&w2s[(n * 16 + l15) * WSTR + kb + quad * 8];
                acc2[n] = __builtin_amdgcn_mfma_f32_16x16x32_bf16(a2, b, acc2[n], 0, 0, 0);
            }
        }
#pragma unroll
        for (int n = 0; n < 8; n++) {
#pragma unroll
            for (int r = 0; r < 4; r++) {
                int row = row0 + quad * 4 + r;
                if (row < N_NODES)
                    out[row * DIM + n * 16 + l15] = acc2[n][r] + b2v[n];
            }
        }
    }
}

extern "C" void kernel_launch(void* const* d_in, const int* in_sizes, int n_in,
                              void* d_out, int out_size, void* d_ws, size_t ws_size,
                              hipStream_t stream) {
    const float* feat = (const float*)d_in[0];
    const int* src    = (const int*)d_in[1];
    const int* dst    = (const int*)d_in[2];
    const float* eps  = (const float*)d_in[3];
    const float* W1   = (const float*)d_in[4];
    const float* b1   = (const float*)d_in[5];
    const float* W2   = (const float*)d_in[6];
    const float* b2   = (const float*)d_in[7];
    float* out = (float*)d_out;

    char* ws = (char*)d_ws;
    int*      bincnt  = (int*)ws;                          //     1,564 B -> 2,048
    int*      rowptr  = (int*)(ws + 2048);                 //   401,408 B
    int*      csr     = (int*)(ws + 403456);               // 12,800,000 B
    uint32_t* binpair = (uint32_t*)(ws + 13203456);        // 15,915,264 B (391 x 10176 x 4)
    uint32_t* featp   = (uint32_t*)(ws + 29118720);        // 25,600,000 B (2 pass tables)
    uint32_t* hbf     = (uint32_t*)(ws + 54718720);        // 25,608,192 B
    short*    w1t     = (short*)(ws + 80326912);           //     32,768 B
    short*    w2t     = (short*)(ws + 80359680);           // ends 80,392,448 B
    // ghist/goff alias the hbf region (dead until gather; 2 x 1,223,048 B)
    int*      ghist   = (int*)(ws + 54718720);
    int*      goff    = (int*)(ws + 54718720 + 1223168);

    prep_kernel<<<12564, 256, 0, stream>>>(feat, featp, W1, W2, w1t, w2t);
    hist_kernel<<<NBLK, 256, 0, stream>>>(dst, ghist);
    offset_kernel<<<NBINS, 1024, 0, stream>>>(ghist, goff, bincnt);
    bin_kernel<<<NBLK, 256, 0, stream>>>(src, dst, goff, binpair);
    csr_kernel<<<NBINS, 1024, 0, stream>>>(bincnt, binpair, rowptr, csr);
    gather_kernel<<<NPAD / 4, 256, 0, stream>>>(featp, rowptr, csr, eps, hbf, 0);
    gather_kernel<<<NPAD / 4, 256, 0, stream>>>(featp + PASSU32, rowptr, csr, eps, hbf, 32);
    mlp_kernel<<<256, 512, 0, stream>>>((const short*)hbf, w1t, w2t, b1, b2, out);
}